// Round 14
// baseline (531.066 us; speedup 1.0000x reference)
//
#include <hip/hip_runtime.h>
#include <hip/hip_bf16.h>

// Device buffers are FLOAT32 (confirmed R4/R5). bf16 MFMA compute, f32 accum.
// R13->R14: ONLY change = drop the min-waves arg from attn launch_bounds.
// R13's (512,2) made hipcc cap VGPR at 128 -> ~120 spilled regs -> 165 MB
// scratch writes (3rd occurrence of this trap). Body needs ~250 VGPR; with
// 146 KB LDS we get 1 block/CU = 8 waves = 2/SIMD naturally (2x250 <= 512).

typedef __attribute__((ext_vector_type(8))) short short8_t;
typedef __attribute__((ext_vector_type(2))) unsigned uint2_t;
typedef __attribute__((ext_vector_type(8))) __bf16 bf16x8;
typedef __attribute__((ext_vector_type(4))) float f32x4;
typedef __attribute__((ext_vector_type(16))) float f32x16;

#define SEQLEN 2048
#define QSCALE 0.08838834764831845f   // HEAD_DIM^-0.5, folded into Q at RoPE

__device__ __forceinline__ short f2b(float f) {
  if (!__builtin_isfinite(f)) f = 0.0f;   // diagnostic scrub (final stores only)
  union { float f; unsigned u; } v; v.f = f;
  unsigned r = (v.u + 0x7fffu + ((v.u >> 16) & 1u)) >> 16;  // RNE
  return (short)r;
}
__device__ __forceinline__ float sf(float f) {
  return __builtin_isfinite(f) ? f : 0.0f;
}
__device__ __forceinline__ short8_t cvt8(const float* p) {
  f32x4 a = *(const f32x4*)p;
  f32x4 b = *(const f32x4*)(p + 4);
  short8_t o;
  o[0] = f2b(a[0]); o[1] = f2b(a[1]); o[2] = f2b(a[2]); o[3] = f2b(a[3]);
  o[4] = f2b(b[0]); o[5] = f2b(b[1]); o[6] = f2b(b[2]); o[7] = f2b(b[3]);
  return o;
}
// pack two f32 -> (bf16 hi<<16 | bf16 lo); inputs finite by construction
__device__ __forceinline__ unsigned pkb(float lo, float hi) {
  union { float f; unsigned u; } a, b; a.f = lo; b.f = hi;
  unsigned ra = (a.u + 0x7fffu + ((a.u >> 16) & 1u)) >> 16;
  unsigned rb = (b.u + 0x7fffu + ((b.u >> 16) & 1u)) & 0xffff0000u;
  return rb | ra;
}

#define GLD16(gp, lp) __builtin_amdgcn_global_load_lds( \
    (const __attribute__((address_space(1))) void*)(gp), \
    (__attribute__((address_space(3))) void*)(lp), 16, 0, 0)

// ---------------------------------------------------------------------------
__global__ __launch_bounds__(256) void cvt_bf16(
    const float* __restrict__ in, short* __restrict__ out)
{
  size_t i = ((size_t)blockIdx.x * 256 + threadIdx.x) * 8;
  *(short8_t*)&out[i] = cvt8(in + i);
}

// ---------------------------------------------------------------------------
// GEMM: C[m][n] = sum_k A[m][k]*W[n][k], A/W bf16, C f32. m97 structure.
// ---------------------------------------------------------------------------
__global__ __launch_bounds__(256) void gemm_bf(
    const short* __restrict__ A, const short* __restrict__ W,
    float* __restrict__ C1, float* __restrict__ C2,
    int K, int ldc, int splitN)
{
  __shared__ short As[128 * 64];
  __shared__ short Ws[128 * 64];
  const int tid  = threadIdx.x;
  const int lane = tid & 63;
  const int wid  = tid >> 6;
  const int l15  = lane & 15;
  const int l4   = lane >> 4;

  const int nwg = (int)(gridDim.x * gridDim.y);
  int bid = (int)(blockIdx.y * gridDim.x + blockIdx.x);
  int swz = (bid & 7) * (nwg >> 3) + (bid >> 3);
  const int m0 = (swz / (int)gridDim.x) * 128;
  const int n0 = (swz % (int)gridDim.x) * 128;

  const int wr = (wid >> 1) * 64;
  const int wc = (wid & 1) * 64;
  const int srow = tid >> 3;
  const int scol = (tid & 7) * 8;

  f32x4 acc[4][4] = {};

  const short* Ab = A + (size_t)(m0 + srow) * K + scol;
  const short* Wb = W + (size_t)(n0 + srow) * K + scol;

  for (int k0 = 0; k0 < K; k0 += 64) {
#pragma unroll
    for (int i = 0; i < 4; ++i) {
      GLD16(Ab + (size_t)(i * 32) * K + k0, &As[(i * 32 + wid * 8) * 64]);
      GLD16(Wb + (size_t)(i * 32) * K + k0, &Ws[(i * 32 + wid * 8) * 64]);
    }
    __syncthreads();

#pragma unroll
    for (int kk = 0; kk < 2; ++kk) {
      bf16x8 af[4], wf[4];
#pragma unroll
      for (int m = 0; m < 4; ++m)
        af[m] = *(const bf16x8*)&As[(wr + m * 16 + l15) * 64 + kk * 32 + l4 * 8];
#pragma unroll
      for (int n = 0; n < 4; ++n)
        wf[n] = *(const bf16x8*)&Ws[(wc + n * 16 + l15) * 64 + kk * 32 + l4 * 8];
#pragma unroll
      for (int m = 0; m < 4; ++m)
#pragma unroll
        for (int n = 0; n < 4; ++n)
          acc[m][n] = __builtin_amdgcn_mfma_f32_16x16x32_bf16(af[m], wf[n], acc[m][n], 0, 0, 0);
    }
    __syncthreads();
  }

  float* Cb = (n0 < splitN) ? C1 : (C2 - splitN);
#pragma unroll
  for (int m = 0; m < 4; ++m) {
    int rbase = m0 + wr + m * 16 + l4 * 4;
#pragma unroll
    for (int n = 0; n < 4; ++n) {
      int cbase = n0 + wc + n * 16 + l15;
#pragma unroll
      for (int r = 0; r < 4; ++r)
        Cb[(size_t)(rbase + r) * ldc + cbase] = sf(acc[m][n][r]);
    }
  }
}

// ---------------------------------------------------------------------------
// RoPE
// ---------------------------------------------------------------------------
__device__ __forceinline__ void rope8(const float* in, float* out,
                                      const float* fc, const float* fs, int t, int p0)
{
  f32x4 a = *(const f32x4*)in;
  f32x4 b = *(const f32x4*)(in + 4);
  f32x4 cv = *(const f32x4*)&fc[t * 64 + p0];
  f32x4 sv = *(const f32x4*)&fs[t * 64 + p0];
  float x0[8] = {a[0], a[1], a[2], a[3], b[0], b[1], b[2], b[3]};
#pragma unroll
  for (int i = 0; i < 4; ++i) {
    float xr = x0[2 * i], xi = x0[2 * i + 1];
    out[2 * i]     = sf(xr * cv[i] - xi * sv[i]);
    out[2 * i + 1] = sf(xr * sv[i] + xi * cv[i]);
  }
}

__global__ __launch_bounds__(256) void rope_q_bf(
    const float* __restrict__ q, short* __restrict__ qb,
    const float* __restrict__ fc, const float* __restrict__ fs)
{
  size_t idx = ((size_t)blockIdx.x * 256 + threadIdx.x) * 8;
  int t   = (int)(idx >> 12);
  int col = (int)(idx & 4095);
  float o[8];
  rope8(&q[idx], o, fc, fs, t, (col & 127) >> 1);
  short8_t ob;
#pragma unroll
  for (int i = 0; i < 8; ++i) ob[i] = f2b(o[i] * QSCALE);
  *(short8_t*)&qb[idx] = ob;
}

__global__ __launch_bounds__(256) void rope_k_dual(
    float* __restrict__ ck, short* __restrict__ kb,
    const float* __restrict__ fc, const float* __restrict__ fs)
{
  size_t idx = ((size_t)blockIdx.x * 256 + threadIdx.x) * 8;
  int t   = (int)(idx >> 10);
  int col = (int)(idx & 1023);
  float o[8];
  rope8(&ck[idx], o, fc, fs, t, (col & 127) >> 1);
  *(f32x4*)&ck[idx]     = f32x4{o[0], o[1], o[2], o[3]};
  *(f32x4*)&ck[idx + 4] = f32x4{o[4], o[5], o[6], o[7]};
  short8_t ob;
#pragma unroll
  for (int i = 0; i < 8; ++i) ob[i] = f2b(o[i]);
  *(short8_t*)&kb[idx] = ob;
}

// cache_v f32 [2048][8*128] -> Vt bf16 [8][128][2048]
__global__ __launch_bounds__(256) void transpose_v(
    const float* __restrict__ cv, short* __restrict__ Vt)
{
  __shared__ short tile[64][72];
  const int t0 = blockIdx.x * 64;
  const int d0 = blockIdx.y * 64;
  const int h  = blockIdx.z;
  const int tid = threadIdx.x;
  const int r = tid >> 3;
  const int c = (tid & 7) * 8;
#pragma unroll
  for (int it = 0; it < 2; ++it) {
    short8_t v = cvt8(&cv[(size_t)(t0 + it * 32 + r) * 1024 + h * 128 + d0 + c]);
    *(short8_t*)&tile[it * 32 + r][c] = v;
  }
  __syncthreads();
#pragma unroll
  for (int it = 0; it < 2; ++it) {
    int dr = it * 32 + r;
    short8_t v;
#pragma unroll
    for (int i = 0; i < 8; ++i) v[i] = tile[c + i][dr];
    *(short8_t*)&Vt[(size_t)(h * 128 + d0 + dr) * SEQLEN + t0 + c] = v;
  }
}

// ---------------------------------------------------------------------------
// Causal flash attention, swapped-QK^T 32x32. Grid 256 x 512 threads.
// Block = (kvh, i): 8 waves = 4 heads x 2 KV-parities. Superstep stages
// 128 keys of K [128][128] + V [128][128] (chunk ^= row&15 swizzle, both
// sides); parity p computes tiles kt = ktb + p*64. Per-wave q-tiles
// A=63-i, B=i. In-block flash merge of the two parities per head.
// Lane state: q = lane&31, S^T keys = crow(r,hi) = (r&3)+8*(r>>2)+4*hi.
// NOTE: NO min-waves arg in launch_bounds (R11/R13 spill trap).
// ---------------------------------------------------------------------------
__global__ __launch_bounds__(512) void attn_fwd6(
    const short* __restrict__ Q,    // [2048][4096] bf16, pre-scaled
    const short* __restrict__ Kc,   // [2048][1024] bf16
    const short* __restrict__ Vt,   // [8][128][2048] bf16
    short* __restrict__ O)          // [2048][4096] bf16
{
  const int bid = (int)blockIdx.x;
  const int kvh = bid & 7;
  const int i   = bid >> 3;             // 0..31
  const int qtA = 63 - i, qtB = i;
  const int tid = (int)threadIdx.x;
  const int wid = tid >> 6;             // 0..7
  const int hs  = wid & 3;              // head slot
  const int par = wid >> 2;             // KV parity
  const int h   = kvh * 4 + hs;
  const int lane = tid & 63;
  const int l31 = lane & 31;
  const int hi  = lane >> 5;

  __shared__ short Ks[128 * 128];       // 32 KB, [key][d-chunk ^ key&15]
  __shared__ short Vs[128 * 128];       // 32 KB, [d][key-chunk ^ d&15]
  __shared__ short PA[8][32][72], PB[8][32][72];   // 73.7 KB
  __shared__ float exch[8][64];
  __shared__ float mlx[2][4][2][32][2]; // [par][hs][tile][q][{m,l}]
  __shared__ float scx[2][4][2][32];

  const int q0A = qtA * 32, q0B = qtB * 32;
  const int qgA = q0A + l31, qgB = q0B + l31;
  const int kendA = q0A + 32, kendB = q0B + 32;

  bf16x8 qfA[8], qfB[8];
  {
    const short* qpA = Q + (size_t)qgA * 4096 + h * 128 + hi * 8;
    const short* qpB = Q + (size_t)qgB * 4096 + h * 128 + hi * 8;
#pragma unroll
    for (int ks = 0; ks < 8; ++ks) {
      qfA[ks] = *(const bf16x8*)(qpA + ks * 16);
      qfB[ks] = *(const bf16x8*)(qpB + ks * 16);
    }
  }

  f32x16 oA0 = {}, oA1 = {}, oA2 = {}, oA3 = {};
  f32x16 oB0 = {}, oB1 = {}, oB2 = {}, oB3 = {};
  float mA = -1e30f, lA = 0.f, mB = -1e30f, lB = 0.f;

  const int xsw = l31 & 15;             // read-side swizzle

  for (int ktb = 0; ktb < kendA; ktb += 128) {
    // ---- stage 128-key superstep (all 8 waves; 4 K + 4 V loads each) ----
#pragma unroll
    for (int it = 0; it < 4; ++it) {
      int g0  = (wid * 4 + it) * 64;    // chunk base (wave-uniform)
      int row = (g0 >> 4) + (lane >> 4);
      int gch = (lane & 15) ^ (row & 15);
      GLD16(Kc + (size_t)(ktb + row) * 1024 + kvh * 128 + gch * 8, &Ks[g0 * 8]);
      GLD16(Vt + (size_t)(kvh * 128 + row) * SEQLEN + ktb + gch * 8, &Vs[g0 * 8]);
    }
    __syncthreads();

    const int kt = ktb + par * 64;
    if (kt < kendA) {
      const int kb = par * 64;          // Ks row base for this parity
      const bool actB = (kt < kendB);
      f32x16 sA0 = {}, sA1 = {}, sB0 = {}, sB1 = {};
      {
        __builtin_amdgcn_s_setprio(1);
#pragma unroll
        for (int ks = 0; ks < 8; ++ks) {
          int ch = (ks * 2 + hi) ^ xsw;
          bf16x8 k0 = *(const bf16x8*)&Ks[(kb + l31) * 128 + ch * 8];
          bf16x8 k1 = *(const bf16x8*)&Ks[(kb + 32 + l31) * 128 + ch * 8];
          sA0 = __builtin_amdgcn_mfma_f32_32x32x16_bf16(k0, qfA[ks], sA0, 0, 0, 0);
          sA1 = __builtin_amdgcn_mfma_f32_32x32x16_bf16(k1, qfA[ks], sA1, 0, 0, 0);
          if (actB) {
            sB0 = __builtin_amdgcn_mfma_f32_32x32x16_bf16(k0, qfB[ks], sB0, 0, 0, 0);
            sB1 = __builtin_amdgcn_mfma_f32_32x32x16_bf16(k1, qfB[ks], sB1, 0, 0, 0);
          }
        }
        __builtin_amdgcn_s_setprio(0);
      }

      // ----- tile A softmax -----
      if (kt + 63 > q0A) {
#pragma unroll
        for (int r = 0; r < 16; ++r) {
          int crow = (r & 3) + 8 * (r >> 2) + 4 * hi;
          if (kt + crow > qgA)      sA0[r] = -1e30f;
          if (kt + 32 + crow > qgA) sA1[r] = -1e30f;
        }
      }
      {
        float t[8];
#pragma unroll
        for (int r = 0; r < 8; ++r)
          t[r] = fmaxf(fmaxf(sA0[r], sA0[r + 8]), fmaxf(sA1[r], sA1[r + 8]));
        float pmax = fmaxf(fmaxf(fmaxf(t[0], t[1]), fmaxf(t[2], t[3])),
                           fmaxf(fmaxf(t[4], t[5]), fmaxf(t[6], t[7])));
        pmax = fmaxf(pmax, __shfl_xor(pmax, 32, 64));
        if (!__all(pmax <= mA + 8.f)) {
          float mnew = fmaxf(mA, pmax);
          float resc = __expf(mA - mnew);
          mA = mnew; lA *= resc;
          if (lane < 32) exch[wid][l31] = resc;
#pragma unroll
          for (int r = 0; r < 16; ++r) {
            float rs = exch[wid][(r & 3) + 8 * (r >> 2) + 4 * hi];
            oA0[r] *= rs; oA1[r] *= rs; oA2[r] *= rs; oA3[r] *= rs;
          }
        }
        float psum = 0.f;
#pragma unroll
        for (int r = 0; r < 16; ++r) { sA0[r] = __expf(sA0[r] - mA); psum += sA0[r]; }
#pragma unroll
        for (int r = 0; r < 16; ++r) { sA1[r] = __expf(sA1[r] - mA); psum += sA1[r]; }
        lA += psum + __shfl_xor(psum, 32, 64);
#pragma unroll
        for (int t4 = 0; t4 < 4; ++t4) {
          int c = 8 * t4 + 4 * hi;
          *(uint2_t*)&PA[wid][l31][c]      = uint2_t{pkb(sA0[4*t4], sA0[4*t4+1]), pkb(sA0[4*t4+2], sA0[4*t4+3])};
          *(uint2_t*)&PA[wid][l31][32 + c] = uint2_t{pkb(sA1[4*t4], sA1[4*t4+1]), pkb(sA1[4*t4+2], sA1[4*t4+3])};
        }
      }

      // ----- tile B softmax -----
      if (actB) {
        if (kt + 63 > q0B) {
#pragma unroll
          for (int r = 0; r < 16; ++r) {
            int crow = (r & 3) + 8 * (r >> 2) + 4 * hi;
            if (kt + crow > qgB)      sB0[r] = -1e30f;
            if (kt + 32 + crow > qgB) sB1[r] = -1e30f;
          }
        }
        float t[8];
#pragma unroll
        for (int r = 0; r < 8; ++r)
          t[r] = fmaxf(fmaxf(sB0[r], sB0[r + 8]), fmaxf(sB1[r], sB1[r + 8]));
        float pmax = fmaxf(fmaxf(fmaxf(t[0], t[1]), fmaxf(t[2], t[3])),
                           fmaxf(fmaxf(t[4], t[5]), fmaxf(t[6], t[7])));
        pmax = fmaxf(pmax, __shfl_xor(pmax, 32, 64));
        if (!__all(pmax <= mB + 8.f)) {
          float mnew = fmaxf(mB, pmax);
          float resc = __expf(mB - mnew);
          mB = mnew; lB *= resc;
          if (lane < 32) exch[wid][32 + l31] = resc;
#pragma unroll
          for (int r = 0; r < 16; ++r) {
            float rs = exch[wid][32 + (r & 3) + 8 * (r >> 2) + 4 * hi];
            oB0[r] *= rs; oB1[r] *= rs; oB2[r] *= rs; oB3[r] *= rs;
          }
        }
        float psum = 0.f;
#pragma unroll
        for (int r = 0; r < 16; ++r) { sB0[r] = __expf(sB0[r] - mB); psum += sB0[r]; }
#pragma unroll
        for (int r = 0; r < 16; ++r) { sB1[r] = __expf(sB1[r] - mB); psum += sB1[r]; }
        lB += psum + __shfl_xor(psum, 32, 64);
#pragma unroll
        for (int t4 = 0; t4 < 4; ++t4) {
          int c = 8 * t4 + 4 * hi;
          *(uint2_t*)&PB[wid][l31][c]      = uint2_t{pkb(sB0[4*t4], sB0[4*t4+1]), pkb(sB0[4*t4+2], sB0[4*t4+3])};
          *(uint2_t*)&PB[wid][l31][32 + c] = uint2_t{pkb(sB1[4*t4], sB1[4*t4+1]), pkb(sB1[4*t4+2], sB1[4*t4+3])};
        }
      }

      // ----- PV (V-frags from LDS, shared by A and B) -----
#pragma unroll
      for (int g = 0; g < 4; ++g) {
        int chl = par * 8 + g * 2 + hi;   // logical key-chunk
        bf16x8 vf0 = *(const bf16x8*)&Vs[(l31)      * 128 + (chl ^ xsw) * 8];
        bf16x8 vf1 = *(const bf16x8*)&Vs[(32 + l31) * 128 + (chl ^ xsw) * 8];
        bf16x8 vf2 = *(const bf16x8*)&Vs[(64 + l31) * 128 + (chl ^ xsw) * 8];
        bf16x8 vf3 = *(const bf16x8*)&Vs[(96 + l31) * 128 + (chl ^ xsw) * 8];
        bf16x8 pfA = *(const bf16x8*)&PA[wid][l31][g * 16 + hi * 8];
        __builtin_amdgcn_s_setprio(1);
        oA0 = __builtin_amdgcn_mfma_f32_32x32x16_bf16(pfA, vf0, oA0, 0, 0, 0);
        oA1 = __builtin_amdgcn_mfma_f32_32x32x16_bf16(pfA, vf1, oA1, 0, 0, 0);
        oA2 = __builtin_amdgcn_mfma_f32_32x32x16_bf16(pfA, vf2, oA2, 0, 0, 0);
        oA3 = __builtin_amdgcn_mfma_f32_32x32x16_bf16(pfA, vf3, oA3, 0, 0, 0);
        if (actB) {
          bf16x8 pfB = *(const bf16x8*)&PB[wid][l31][g * 16 + hi * 8];
          oB0 = __builtin_amdgcn_mfma_f32_32x32x16_bf16(pfB, vf0, oB0, 0, 0, 0);
          oB1 = __builtin_amdgcn_mfma_f32_32x32x16_bf16(pfB, vf1, oB1, 0, 0, 0);
          oB2 = __builtin_amdgcn_mfma_f32_32x32x16_bf16(pfB, vf2, oB2, 0, 0, 0);
          oB3 = __builtin_amdgcn_mfma_f32_32x32x16_bf16(pfB, vf3, oB3, 0, 0, 0);
        }
        __builtin_amdgcn_s_setprio(0);
      }
    }
    __syncthreads();   // all waves done with Ks/Vs before next stage
  }

  // ----- in-block flash merge of the two parities, per head -----
  if (lane < 32) {
    mlx[par][hs][0][l31][0] = mA; mlx[par][hs][0][l31][1] = lA;
    mlx[par][hs][1][l31][0] = mB; mlx[par][hs][1][l31][1] = lB;
  }
  __syncthreads();
  if (par == 0 && lane < 32) {
#pragma unroll
    for (int T = 0; T < 2; ++T) {
      float m0 = mlx[0][hs][T][l31][0], l0 = mlx[0][hs][T][l31][1];
      float m1 = mlx[1][hs][T][l31][0], l1 = mlx[1][hs][T][l31][1];
      float M  = fmaxf(m0, m1);
      float e0 = __expf(m0 - M), e1 = __expf(m1 - M);
      float den = l0 * e0 + l1 * e1;
      scx[0][hs][T][l31] = e0 / den;
      scx[1][hs][T][l31] = e1 / den;
    }
  }
  __syncthreads();

  float* ox = (float*)(&PA[0][0][0]) + hs * 1024;   // 16x64 f32 per head

#define MERGE_STORE(oreg, T, q0, g) do {                                       \
    if (par == 1) {                                                            \
      _Pragma("unroll")                                                        \
      for (int r = 0; r < 16; ++r)                                             \
        ox[r * 64 + lane] = (oreg)[r] * scx[1][hs][T][(r & 3) + 8 * (r >> 2) + 4 * hi]; \
    }                                                                          \
    __syncthreads();                                                           \
    if (par == 0) {                                                            \
      _Pragma("unroll")                                                        \
      for (int r = 0; r < 16; ++r) {                                           \
        int crow = (r & 3) + 8 * (r >> 2) + 4 * hi;                            \
        float v = (oreg)[r] * scx[0][hs][T][crow] + ox[r * 64 + lane];         \
        O[(size_t)((q0) + crow) * 4096 + h * 128 + (g) * 32 + l31] = f2b(v);   \
      }                                                                        \
    }                                                                          \
    __syncthreads();                                                           \
  } while (0)

  MERGE_STORE(oA0, 0, q0A, 0);
  MERGE_STORE(oA1, 0, q0A, 1);
  MERGE_STORE(oA2, 0, q0A, 2);
  MERGE_STORE(oA3, 0, q0A, 3);
  MERGE_STORE(oB0, 1, q0B, 0);
  MERGE_STORE(oB1, 1, q0B, 1);
  MERGE_STORE(oB2, 1, q0B, 2);
  MERGE_STORE(oB3, 1, q0B, 3);
#undef MERGE_STORE
}

// ---------------------------------------------------------------------------
extern "C" void kernel_launch(void* const* d_in, const int* in_sizes, int n_in,
                              void* d_out, int out_size, void* d_ws, size_t ws_size,
                              hipStream_t stream) {
  const float* x  = (const float*)d_in[0];
  const float* wq = (const float*)d_in[1];
  const float* wk = (const float*)d_in[2];
  const float* wv = (const float*)d_in[3];
  const float* wo = (const float*)d_in[4];
  const float* fc = (const float*)d_in[5];
  const float* fs = (const float*)d_in[6];

  float* out = (float*)d_out;
  float* out_main = out;                               // [2048][4096]
  float* cache_k  = out + (size_t)2048 * 4096;         // [4096][8][128]
  float* cache_v  = cache_k + (size_t)4096 * 8 * 128;  // [4096][8][128]

  const size_t MB_W = 33554432;   // 4096x4096 bf16
  const size_t MB_X = 16777216;   // 2048x4096 bf16
  short* slotA = (short*)d_ws;
  short* x_bf  = (short*)((char*)d_ws + MB_W);
  short* attn_out = x_bf;
  short* Vt    = (short*)((char*)d_ws + MB_W + MB_X);
  short* q_bf  = slotA;
  short* k_bf  = slotA + (size_t)2048 * 4096;

  // converts + projections
  cvt_bf16<<<4096, 256, 0, stream>>>(x, x_bf);
  cvt_bf16<<<8192, 256, 0, stream>>>(wq, slotA);
  gemm_bf<<<dim3(32, 16), 256, 0, stream>>>(x_bf, slotA, out_main, out_main, 4096, 4096, 1 << 30);
  cvt_bf16<<<2048, 256, 0, stream>>>(wk, slotA);
  cvt_bf16<<<2048, 256, 0, stream>>>(wv, slotA + (size_t)1024 * 4096);
  gemm_bf<<<dim3(16, 16), 256, 0, stream>>>(x_bf, slotA, cache_k, cache_v, 4096, 1024, 1024);

  // RoPE + V transpose + cache tail zeros
  rope_q_bf<<<4096, 256, 0, stream>>>(out_main, q_bf, fc, fs);
  rope_k_dual<<<1024, 256, 0, stream>>>(cache_k, k_bf, fc, fs);
  transpose_v<<<dim3(32, 2, 8), 256, 0, stream>>>(cache_v, Vt);
  hipMemsetAsync(cache_k + (size_t)2048 * 1024, 0, (size_t)2048 * 1024 * 4, stream);
  hipMemsetAsync(cache_v + (size_t)2048 * 1024, 0, (size_t)2048 * 1024 * 4, stream);

  // attention: 256 blocks x 8 waves (4 heads x 2 KV-parities)
  attn_fwd6<<<256, 512, 0, stream>>>(q_bf, k_bf, Vt, attn_out);

  // output projection
  cvt_bf16<<<8192, 256, 0, stream>>>(wo, slotA);
  gemm_bf<<<dim3(32, 16), 256, 0, stream>>>(attn_out, slotA, out_main, out_main, 4096, 4096, 1 << 30);
}

// Round 15
// 423.962 us; speedup vs baseline: 1.2526x; 1.2526x over previous
//
#include <hip/hip_runtime.h>
#include <hip/hip_bf16.h>

// Device buffers are FLOAT32 (confirmed R4/R5). bf16 MFMA compute, f32 accum.
// R14->R15: (a) attn: single-q-tile 256-thr blocks (deletion from R12-proven
// attn_fwd5), 512 blocks heavy-first, 51KB LDS -> 3 blocks/CU. 512-thr blocks
// are hard-capped at 128 VGPR on this toolchain (R13/R14) - never again.
// (b) Q-proj/KV-proj GEMMs split-K x2 (grid z=2, 4/CU) with fused
// combine+RoPE kernels; partials live in dead d_out regions.

typedef __attribute__((ext_vector_type(8))) short short8_t;
typedef __attribute__((ext_vector_type(2))) unsigned uint2_t;
typedef __attribute__((ext_vector_type(8))) __bf16 bf16x8;
typedef __attribute__((ext_vector_type(4))) float f32x4;
typedef __attribute__((ext_vector_type(16))) float f32x16;

#define SEQLEN 2048
#define QSCALE 0.08838834764831845f   // HEAD_DIM^-0.5, folded into Q at RoPE

__device__ __forceinline__ short f2b(float f) {
  if (!__builtin_isfinite(f)) f = 0.0f;   // diagnostic scrub (final stores only)
  union { float f; unsigned u; } v; v.f = f;
  unsigned r = (v.u + 0x7fffu + ((v.u >> 16) & 1u)) >> 16;  // RNE
  return (short)r;
}
__device__ __forceinline__ float sf(float f) {
  return __builtin_isfinite(f) ? f : 0.0f;
}
__device__ __forceinline__ short8_t cvt8(const float* p) {
  f32x4 a = *(const f32x4*)p;
  f32x4 b = *(const f32x4*)(p + 4);
  short8_t o;
  o[0] = f2b(a[0]); o[1] = f2b(a[1]); o[2] = f2b(a[2]); o[3] = f2b(a[3]);
  o[4] = f2b(b[0]); o[5] = f2b(b[1]); o[6] = f2b(b[2]); o[7] = f2b(b[3]);
  return o;
}
// pack two f32 -> (bf16 hi<<16 | bf16 lo); inputs finite by construction
__device__ __forceinline__ unsigned pkb(float lo, float hi) {
  union { float f; unsigned u; } a, b; a.f = lo; b.f = hi;
  unsigned ra = (a.u + 0x7fffu + ((a.u >> 16) & 1u)) >> 16;
  unsigned rb = (b.u + 0x7fffu + ((b.u >> 16) & 1u)) & 0xffff0000u;
  return rb | ra;
}

#define GLD16(gp, lp) __builtin_amdgcn_global_load_lds( \
    (const __attribute__((address_space(1))) void*)(gp), \
    (__attribute__((address_space(3))) void*)(lp), 16, 0, 0)

// ---------------------------------------------------------------------------
__global__ __launch_bounds__(256) void cvt_bf16(
    const float* __restrict__ in, short* __restrict__ out)
{
  size_t i = ((size_t)blockIdx.x * 256 + threadIdx.x) * 8;
  *(short8_t*)&out[i] = cvt8(in + i);
}

// ---------------------------------------------------------------------------
// GEMM: C[m][n] = sum_{k in [z*Kloop, (z+1)*Kloop)} A[m][k]*W[n][k].
// A/W bf16 row-major with row stride lda; C f32 (C0 for z=0, C1 for z=1).
// m97 structure: 128x128 tile, BK=64, global_load_lds w16, 4 waves.
// ---------------------------------------------------------------------------
__global__ __launch_bounds__(256) void gemm_bf(
    const short* __restrict__ A, const short* __restrict__ W,
    float* __restrict__ C0, float* __restrict__ C1,
    int Kloop, int lda, int ldc)
{
  __shared__ short As[128 * 64];
  __shared__ short Ws[128 * 64];
  const int tid  = threadIdx.x;
  const int lane = tid & 63;
  const int wid  = tid >> 6;
  const int l15  = lane & 15;
  const int l4   = lane >> 4;

  const int nwg = (int)(gridDim.x * gridDim.y);
  int bid = (int)(blockIdx.y * gridDim.x + blockIdx.x);
  int swz = (bid & 7) * (nwg >> 3) + (bid >> 3);
  const int m0 = (swz / (int)gridDim.x) * 128;
  const int n0 = (swz % (int)gridDim.x) * 128;
  const int koff = (int)blockIdx.z * Kloop;
  float* C = blockIdx.z ? C1 : C0;

  const int wr = (wid >> 1) * 64;
  const int wc = (wid & 1) * 64;
  const int srow = tid >> 3;
  const int scol = (tid & 7) * 8;

  f32x4 acc[4][4] = {};

  const short* Ab = A + (size_t)(m0 + srow) * lda + koff + scol;
  const short* Wb = W + (size_t)(n0 + srow) * lda + koff + scol;

  for (int k0 = 0; k0 < Kloop; k0 += 64) {
#pragma unroll
    for (int i = 0; i < 4; ++i) {
      GLD16(Ab + (size_t)(i * 32) * lda + k0, &As[(i * 32 + wid * 8) * 64]);
      GLD16(Wb + (size_t)(i * 32) * lda + k0, &Ws[(i * 32 + wid * 8) * 64]);
    }
    __syncthreads();

#pragma unroll
    for (int kk = 0; kk < 2; ++kk) {
      bf16x8 af[4], wf[4];
#pragma unroll
      for (int m = 0; m < 4; ++m)
        af[m] = *(const bf16x8*)&As[(wr + m * 16 + l15) * 64 + kk * 32 + l4 * 8];
#pragma unroll
      for (int n = 0; n < 4; ++n)
        wf[n] = *(const bf16x8*)&Ws[(wc + n * 16 + l15) * 64 + kk * 32 + l4 * 8];
#pragma unroll
      for (int m = 0; m < 4; ++m)
#pragma unroll
        for (int n = 0; n < 4; ++n)
          acc[m][n] = __builtin_amdgcn_mfma_f32_16x16x32_bf16(af[m], wf[n], acc[m][n], 0, 0, 0);
    }
    __syncthreads();
  }

#pragma unroll
  for (int m = 0; m < 4; ++m) {
    int rbase = m0 + wr + m * 16 + l4 * 4;
#pragma unroll
    for (int n = 0; n < 4; ++n) {
      int cbase = n0 + wc + n * 16 + l15;
#pragma unroll
      for (int r = 0; r < 4; ++r)
        C[(size_t)(rbase + r) * ldc + cbase] = sf(acc[m][n][r]);
    }
  }
}

// ---------------------------------------------------------------------------
// RoPE on 8 summed values
// ---------------------------------------------------------------------------
__device__ __forceinline__ void rope8v(const float* x0, float* out,
                                       const float* fc, const float* fs, int t, int p0)
{
  f32x4 cv = *(const f32x4*)&fc[t * 64 + p0];
  f32x4 sv = *(const f32x4*)&fs[t * 64 + p0];
#pragma unroll
  for (int i = 0; i < 4; ++i) {
    float xr = x0[2 * i], xi = x0[2 * i + 1];
    out[2 * i]     = sf(xr * cv[i] - xi * sv[i]);
    out[2 * i + 1] = sf(xr * sv[i] + xi * cv[i]);
  }
}

// combine Q split-K partials + RoPE + scale -> q_bf  (2048 x 4096)
__global__ __launch_bounds__(256) void combine_rope_q(
    const float* __restrict__ p0, const float* __restrict__ p1,
    short* __restrict__ qb, const float* __restrict__ fc, const float* __restrict__ fs)
{
  size_t idx = ((size_t)blockIdx.x * 256 + threadIdx.x) * 8;
  int t   = (int)(idx >> 12);
  int col = (int)(idx & 4095);
  f32x4 a0 = *(const f32x4*)&p0[idx],     b0 = *(const f32x4*)&p0[idx + 4];
  f32x4 a1 = *(const f32x4*)&p1[idx],     b1 = *(const f32x4*)&p1[idx + 4];
  float s8[8] = {a0[0]+a1[0], a0[1]+a1[1], a0[2]+a1[2], a0[3]+a1[3],
                 b0[0]+b1[0], b0[1]+b1[1], b0[2]+b1[2], b0[3]+b1[3]};
  float o[8];
  rope8v(s8, o, fc, fs, t, (col & 127) >> 1);
  short8_t ob;
#pragma unroll
  for (int i = 0; i < 8; ++i) ob[i] = f2b(o[i] * QSCALE);
  *(short8_t*)&qb[idx] = ob;
}

// combine KV split-K partials: cols 0..1023 = K (rope -> cache_k f32 + k_bf),
// cols 1024..2047 = V (-> cache_v f32).  (2048 x 2048, ldc 2048)
__global__ __launch_bounds__(256) void combine_rope_kv(
    const float* __restrict__ p0, const float* __restrict__ p1,
    float* __restrict__ ck, short* __restrict__ kb, float* __restrict__ cv,
    const float* __restrict__ fc, const float* __restrict__ fs)
{
  size_t idx = ((size_t)blockIdx.x * 256 + threadIdx.x) * 8;
  int t   = (int)(idx >> 11);
  int col = (int)(idx & 2047);
  f32x4 a0 = *(const f32x4*)&p0[idx],     b0 = *(const f32x4*)&p0[idx + 4];
  f32x4 a1 = *(const f32x4*)&p1[idx],     b1 = *(const f32x4*)&p1[idx + 4];
  float s8[8] = {a0[0]+a1[0], a0[1]+a1[1], a0[2]+a1[2], a0[3]+a1[3],
                 b0[0]+b1[0], b0[1]+b1[1], b0[2]+b1[2], b0[3]+b1[3]};
  if (col < 1024) {
    float o[8];
    rope8v(s8, o, fc, fs, t, (col & 127) >> 1);
    size_t di = (size_t)t * 1024 + col;
    *(f32x4*)&ck[di]     = f32x4{o[0], o[1], o[2], o[3]};
    *(f32x4*)&ck[di + 4] = f32x4{o[4], o[5], o[6], o[7]};
    short8_t ob;
#pragma unroll
    for (int i = 0; i < 8; ++i) ob[i] = f2b(o[i]);
    *(short8_t*)&kb[di] = ob;
  } else {
    size_t di = (size_t)t * 1024 + (col - 1024);
    *(f32x4*)&cv[di]     = f32x4{sf(s8[0]), sf(s8[1]), sf(s8[2]), sf(s8[3])};
    *(f32x4*)&cv[di + 4] = f32x4{sf(s8[4]), sf(s8[5]), sf(s8[6]), sf(s8[7])};
  }
}

// cache_v f32 [2048][8*128] -> Vt bf16 [8][128][2048]
__global__ __launch_bounds__(256) void transpose_v(
    const float* __restrict__ cv, short* __restrict__ Vt)
{
  __shared__ short tile[64][72];
  const int t0 = blockIdx.x * 64;
  const int d0 = blockIdx.y * 64;
  const int h  = blockIdx.z;
  const int tid = threadIdx.x;
  const int r = tid >> 3;
  const int c = (tid & 7) * 8;
#pragma unroll
  for (int it = 0; it < 2; ++it) {
    short8_t v = cvt8(&cv[(size_t)(t0 + it * 32 + r) * 1024 + h * 128 + d0 + c]);
    *(short8_t*)&tile[it * 32 + r][c] = v;
  }
  __syncthreads();
#pragma unroll
  for (int it = 0; it < 2; ++it) {
    int dr = it * 32 + r;
    short8_t v;
#pragma unroll
    for (int i = 0; i < 8; ++i) v[i] = tile[c + i][dr];
    *(short8_t*)&Vt[(size_t)(h * 128 + d0 + dr) * SEQLEN + t0 + c] = v;
  }
}

// ---------------------------------------------------------------------------
// Causal flash attention, swapped-QK^T 32x32, LDS-staged K/V, single q-tile.
// Grid 512 x 256 thr: bid&7 = kvh (XCD pin), j = bid>>3, qt = 63-j (heavy
// first). 4 waves = 4 heads share staged K [64][128] / V [128][64].
// Lane state: q = lane&31, S^T keys = crow(r,hi) = (r&3)+8*(r>>2)+4*hi.
// (Deletion-only derivative of R12-proven attn_fwd5.)
// ---------------------------------------------------------------------------
__global__ __launch_bounds__(256) void attn_fwd7(
    const short* __restrict__ Q,    // [2048][4096] bf16, pre-scaled
    const short* __restrict__ Kc,   // [2048][1024] bf16
    const short* __restrict__ Vt,   // [8][128][2048] bf16
    short* __restrict__ O)          // [2048][4096] bf16
{
  const int bid = (int)blockIdx.x;
  const int kvh = bid & 7;
  const int qt  = 63 - (bid >> 3);
  const int tid = (int)threadIdx.x;
  const int wid = tid >> 6;             // head slot
  const int h   = kvh * 4 + wid;
  const int lane = tid & 63;
  const int l31 = lane & 31;
  const int hi  = lane >> 5;

  __shared__ short Ks[64 * 128];        // [key][d-chunk ^ key&15]
  __shared__ short Vs[128 * 64];        // [d][key-chunk ^ d&7]
  __shared__ short P[4][32][72];
  __shared__ float exch[4][32];

  const int q0 = qt * 32;
  const int qg = q0 + l31;
  const int kend = q0 + 32;

  bf16x8 qf[8];
  {
    const short* qp = Q + (size_t)qg * 4096 + h * 128 + hi * 8;
#pragma unroll
    for (int ks = 0; ks < 8; ++ks) qf[ks] = *(const bf16x8*)(qp + ks * 16);
  }

  f32x16 o0 = {}, o1 = {}, o2 = {}, o3 = {};
  float m = -1e30f, l = 0.f;

  const int krow_base = wid * 16;
  const int vrow_base = wid * 32;
  const int xk = l31 & 15;
  const int xv = l31 & 7;

  for (int kt = 0; kt < kend; kt += 64) {
#pragma unroll
    for (int it = 0; it < 4; ++it) {
      int krow = krow_base + it * 4 + (lane >> 4);
      int kch  = (lane & 15) ^ (krow & 15);
      GLD16(Kc + (size_t)(kt + krow) * 1024 + kvh * 128 + kch * 8,
            &Ks[wid * 2048 + it * 512]);
      int vrow = vrow_base + it * 8 + (lane >> 3);
      int vch  = (lane & 7) ^ (vrow & 7);
      GLD16(Vt + (size_t)(kvh * 128 + vrow) * SEQLEN + kt + vch * 8,
            &Vs[wid * 2048 + it * 512]);
    }
    __syncthreads();

    f32x16 s0 = {}, s1 = {};
    {
      __builtin_amdgcn_s_setprio(1);
#pragma unroll
      for (int ks = 0; ks < 8; ++ks) {
        int ch = (ks * 2 + hi) ^ xk;
        bf16x8 k0 = *(const bf16x8*)&Ks[l31 * 128 + ch * 8];
        bf16x8 k1 = *(const bf16x8*)&Ks[(32 + l31) * 128 + ch * 8];
        s0 = __builtin_amdgcn_mfma_f32_32x32x16_bf16(k0, qf[ks], s0, 0, 0, 0);
        s1 = __builtin_amdgcn_mfma_f32_32x32x16_bf16(k1, qf[ks], s1, 0, 0, 0);
      }
      __builtin_amdgcn_s_setprio(0);
    }

    if (kt + 63 > q0) {
#pragma unroll
      for (int r = 0; r < 16; ++r) {
        int crow = (r & 3) + 8 * (r >> 2) + 4 * hi;
        if (kt + crow > qg)      s0[r] = -1e30f;
        if (kt + 32 + crow > qg) s1[r] = -1e30f;
      }
    }
    {
      float t[8];
#pragma unroll
      for (int r = 0; r < 8; ++r)
        t[r] = fmaxf(fmaxf(s0[r], s0[r + 8]), fmaxf(s1[r], s1[r + 8]));
      float pmax = fmaxf(fmaxf(fmaxf(t[0], t[1]), fmaxf(t[2], t[3])),
                         fmaxf(fmaxf(t[4], t[5]), fmaxf(t[6], t[7])));
      pmax = fmaxf(pmax, __shfl_xor(pmax, 32, 64));
      if (!__all(pmax <= m + 8.f)) {
        float mnew = fmaxf(m, pmax);
        float resc = __expf(m - mnew);
        m = mnew; l *= resc;
        if (lane < 32) exch[wid][l31] = resc;
#pragma unroll
        for (int r = 0; r < 16; ++r) {
          float rs = exch[wid][(r & 3) + 8 * (r >> 2) + 4 * hi];
          o0[r] *= rs; o1[r] *= rs; o2[r] *= rs; o3[r] *= rs;
        }
      }
      float psum = 0.f;
#pragma unroll
      for (int r = 0; r < 16; ++r) { s0[r] = __expf(s0[r] - m); psum += s0[r]; }
#pragma unroll
      for (int r = 0; r < 16; ++r) { s1[r] = __expf(s1[r] - m); psum += s1[r]; }
      l += psum + __shfl_xor(psum, 32, 64);
#pragma unroll
      for (int t4 = 0; t4 < 4; ++t4) {
        int c = 8 * t4 + 4 * hi;
        *(uint2_t*)&P[wid][l31][c]      = uint2_t{pkb(s0[4*t4], s0[4*t4+1]), pkb(s0[4*t4+2], s0[4*t4+3])};
        *(uint2_t*)&P[wid][l31][32 + c] = uint2_t{pkb(s1[4*t4], s1[4*t4+1]), pkb(s1[4*t4+2], s1[4*t4+3])};
      }
    }

#pragma unroll
    for (int g = 0; g < 4; ++g) {
      int ch = (g * 2 + hi) ^ xv;
      bf16x8 vf0 = *(const bf16x8*)&Vs[(l31)      * 64 + ch * 8];
      bf16x8 vf1 = *(const bf16x8*)&Vs[(32 + l31) * 64 + ch * 8];
      bf16x8 vf2 = *(const bf16x8*)&Vs[(64 + l31) * 64 + ch * 8];
      bf16x8 vf3 = *(const bf16x8*)&Vs[(96 + l31) * 64 + ch * 8];
      bf16x8 pf  = *(const bf16x8*)&P[wid][l31][g * 16 + hi * 8];
      __builtin_amdgcn_s_setprio(1);
      o0 = __builtin_amdgcn_mfma_f32_32x32x16_bf16(pf, vf0, o0, 0, 0, 0);
      o1 = __builtin_amdgcn_mfma_f32_32x32x16_bf16(pf, vf1, o1, 0, 0, 0);
      o2 = __builtin_amdgcn_mfma_f32_32x32x16_bf16(pf, vf2, o2, 0, 0, 0);
      o3 = __builtin_amdgcn_mfma_f32_32x32x16_bf16(pf, vf3, o3, 0, 0, 0);
      __builtin_amdgcn_s_setprio(0);
    }
    __syncthreads();
  }

  if (lane < 32) exch[wid][l31] = 1.f / l;
#pragma unroll
  for (int r = 0; r < 16; ++r) {
    int crow = (r & 3) + 8 * (r >> 2) + 4 * hi;
    float inv = exch[wid][crow];
    short* ob = O + (size_t)(q0 + crow) * 4096 + h * 128 + l31;
    ob[0]  = f2b(o0[r] * inv);
    ob[32] = f2b(o1[r] * inv);
    ob[64] = f2b(o2[r] * inv);
    ob[96] = f2b(o3[r] * inv);
  }
}

// ---------------------------------------------------------------------------
extern "C" void kernel_launch(void* const* d_in, const int* in_sizes, int n_in,
                              void* d_out, int out_size, void* d_ws, size_t ws_size,
                              hipStream_t stream) {
  const float* x  = (const float*)d_in[0];
  const float* wq = (const float*)d_in[1];
  const float* wk = (const float*)d_in[2];
  const float* wv = (const float*)d_in[3];
  const float* wo = (const float*)d_in[4];
  const float* fc = (const float*)d_in[5];
  const float* fs = (const float*)d_in[6];

  float* out = (float*)d_out;
  float* out_main = out;                               // [2048][4096] f32
  float* cache_k  = out + (size_t)2048 * 4096;         // [4096][8][128] f32
  float* cache_v  = cache_k + (size_t)4096 * 8 * 128;

  // ws 54.5MB: slotA 33.5 | slotB 16.8 | slotC 4.2
  short* slotA = (short*)d_ws;                         // wq_bf / q_bf+k_bf / wo_bf
  short* slotB = (short*)((char*)d_ws + 33554432);     // x_bf / attn_out
  short* Vt    = (short*)((char*)d_ws + 33554432 + 16777216);
  short* x_bf  = slotB;
  short* attn_out = slotB;
  short* q_bf  = slotA;                                // 16.8MB
  short* wkv_bf = slotA + (size_t)2048 * 4096;         // wk_bf+wv_bf (16.8MB)
  short* k_bf  = slotA + (size_t)2048 * 4096;          // later overwrites wkv_bf

  // split-K partial buffers (f32) in dead d_out regions:
  float* pQ0 = out_main;                               // 33.5MB
  float* pQ1 = cache_k;                                // 33.5MB (ck+cv region)
  float* pKV0 = out_main;                              // 16.8MB (Q partials dead)
  float* pKV1 = out_main + (size_t)2048 * 2048;        // 16.8MB

  // 1) converts + Q projection (split-K x2) + fused combine+rope -> q_bf
  cvt_bf16<<<4096, 256, 0, stream>>>(x, x_bf);
  cvt_bf16<<<8192, 256, 0, stream>>>(wq, slotA);
  gemm_bf<<<dim3(32, 16, 2), 256, 0, stream>>>(x_bf, slotA, pQ0, pQ1, 2048, 4096, 4096);
  combine_rope_q<<<4096, 256, 0, stream>>>(pQ0, pQ1, q_bf, fc, fs);

  // 2) KV projection (split-K x2) + fused combine+rope -> caches + k_bf
  cvt_bf16<<<2048, 256, 0, stream>>>(wk, wkv_bf);
  cvt_bf16<<<2048, 256, 0, stream>>>(wv, wkv_bf + (size_t)1024 * 4096);
  gemm_bf<<<dim3(16, 16, 2), 256, 0, stream>>>(x_bf, wkv_bf, pKV0, pKV1, 2048, 4096, 2048);
  combine_rope_kv<<<2048, 256, 0, stream>>>(pKV0, pKV1, cache_k, k_bf, cache_v, fc, fs);
  transpose_v<<<dim3(32, 2, 8), 256, 0, stream>>>(cache_v, Vt);
  hipMemsetAsync(cache_k + (size_t)2048 * 1024, 0, (size_t)2048 * 1024 * 4, stream);
  hipMemsetAsync(cache_v + (size_t)2048 * 1024, 0, (size_t)2048 * 1024 * 4, stream);

  // 3) attention: 512 single-q-tile blocks, heavy-first, XCD-pinned
  attn_fwd7<<<512, 256, 0, stream>>>(q_bf, k_bf, Vt, attn_out);

  // 4) output projection (full K, single dispatch)
  cvt_bf16<<<8192, 256, 0, stream>>>(wo, slotA);
  gemm_bf<<<dim3(32, 16, 1), 256, 0, stream>>>(attn_out, slotA, out_main, out_main, 4096, 4096, 4096);
}